// Round 12
// baseline (94.834 us; speedup 1.0000x reference)
//
#include <hip/hip_runtime.h>
#include <hip/hip_bf16.h>

typedef __attribute__((ext_vector_type(8))) __bf16 bf16x8;
typedef __attribute__((ext_vector_type(4))) __bf16 bf16x4;
typedef __attribute__((ext_vector_type(4))) float f32x4;

#define DIN 1024
#define DOUT 1024
#define BB 4
#define SS 4096
#define MROWS (BB*SS)   /* 16384 */
#define POOLN 5
#define RR 8
#define NTASKS 5
#define TOPKK 3

// ---------------- KA: colsum partials (pure 64MB read, 2-stream MLP) ----------
// 2048 blocks x 256 threads. Stream A = first 32MB, stream B = second 32MB,
// each contiguous-coalesced float4, prefetch-by-one -> 4 loads in flight.
// Strides and bases ==0 mod 256 float4 -> thread's 4 columns constant.
__global__ __launch_bounds__(256) void kA_colsum(const float* __restrict__ in,
                                                 float* __restrict__ partial) {
    const int t = threadIdx.x;
    const int b = blockIdx.x;
    const int tid = b * 256 + t;                         // 0..524287
    const f32x4* __restrict__ inv = (const f32x4*)in;

    float s0 = 0.f, s1 = 0.f, s2 = 0.f, s3 = 0.f;
    size_t ia = (size_t)tid;                             // stream A
    size_t ib = (size_t)tid + 2097152;                   // stream B
    f32x4 ca = inv[ia];
    f32x4 cb = inv[ib];
#pragma unroll
    for (int i = 0; i < 4; ++i) {
        f32x4 na = ca, nb = cb;
        if (i < 3) {
            na = inv[ia + 524288];
            nb = inv[ib + 524288];
        }
        s0 += ca[0] + cb[0]; s1 += ca[1] + cb[1];
        s2 += ca[2] + cb[2]; s3 += ca[3] + cb[3];
        ca = na; cb = nb;
        ia += 524288; ib += 524288;
    }
    const int c0 = (t * 4) & (DIN - 1);
    f32x4 p = { s0, s1, s2, s3 };
    *(f32x4*)&partial[(size_t)b * DIN + c0] = p;
}

// ---------------- K1b: reduce partial[2048][1024] -> partial2[8][1024] --------
__global__ __launch_bounds__(256) void k1b_reduce(const float* __restrict__ partial,
                                                  float* __restrict__ partial2) {
    const int tid = blockIdx.x * 256 + threadIdx.x;      // 0..8191
    const int c = tid & (DIN - 1);
    const int g = tid >> 10;                             // 0..7
    float s = 0.f;
    const int r0 = g * 256;
#pragma unroll 8
    for (int r = r0; r < r0 + 256; ++r)
        s += partial[(size_t)r * DIN + c];
    partial2[(size_t)g * DIN + c] = s;
}

// ---------------- K23: gate (redundant per block) + weight build --------------
// 1024 blocks x 256 threads. Each block recomputes omegas/top-k/softmax from
// partial2 (32KB) + route (20KB) — L2-served, ~1.5us aggregate — then builds
// its output row of Wb0/Wb1. Removes the k2 kernel node entirely.
__global__ __launch_bounds__(256) void k23_weights(const float* __restrict__ partial2,
                                                   const float* __restrict__ lroute,
                                                   const int* __restrict__ task_id_p,
                                                   const float* __restrict__ W,
                                                   const float* __restrict__ ldown,
                                                   const float* __restrict__ lup,
                                                   __bf16* __restrict__ Wb0,
                                                   __bf16* __restrict__ Wb1) {
    __shared__ float red[4][POOLN];
    __shared__ float sgate[TOPKK];
    __shared__ int   sgidx[TOPKK];
    const int tix = threadIdx.x;
    const int w = tix >> 6, l = tix & 63;

    // ---- omegas: thread covers d = tix*4 .. tix*4+3
    float part[POOLN] = {0.f, 0.f, 0.f, 0.f, 0.f};
    {
        const int d0 = tix * 4;
#pragma unroll
        for (int dd = 0; dd < 4; ++dd) {
            const int d = d0 + dd;
            float cs = 0.f;
#pragma unroll
            for (int g = 0; g < 8; ++g) cs += partial2[g * DIN + d];
            cs *= (1.0f / (float)MROWS);
            const float* rp = &lroute[(size_t)1 * DIN * POOLN + (size_t)d * POOLN];
#pragma unroll
            for (int p = 0; p < POOLN; ++p) part[p] += cs * rp[p];
        }
    }
#pragma unroll
    for (int p = 0; p < POOLN; ++p) {
        float v = part[p];
        for (int off = 32; off; off >>= 1) v += __shfl_down(v, off);
        if (l == 0) red[w][p] = v;
    }
    __syncthreads();
    if (tix == 0) {
#pragma unroll
        for (int p = 0; p < POOLN; ++p)
            part[p] = red[0][p] + red[1][p] + red[2][p] + red[3][p];
        int tid = *task_id_p;
        if (tid > NTASKS) tid = NTASKS;
        int L = tid < (POOLN - 1) ? tid : (POOLN - 1);   // slice [1:tid+1] clamps
        int k = tid < TOPKK ? tid : TOPKK;
        float sl[POOLN];
        for (int j = 0; j < L; ++j) sl[j] = part[1 + j];
        float G[TOPKK]; int I[TOPKK];
        int used = 0;
        for (int j = 0; j < k; ++j) {
            int best = -1; float bv = 0.f;
            for (int i2 = 0; i2 < L; ++i2) {
                if (used & (1 << i2)) continue;
                if (best < 0 || sl[i2] > bv) { bv = sl[i2]; best = i2; }
            }
            used |= 1 << best; G[j] = bv; I[j] = best;
        }
        float gt[TOPKK] = {0.f, 0.f, 0.f};
        int   gi[TOPKK] = {0, 0, 0};
        if (k > 0) {
            float m = G[0];           // descending -> max first
            float e[TOPKK]; float se = 0.f;
            for (int j = 0; j < k; ++j) { e[j] = expf(G[j] - m); se += e[j]; }
            for (int j = 0; j < k; ++j) { gt[j] = e[j] / se; gi[j] = I[j]; }
        }
#pragma unroll
        for (int j = 0; j < TOPKK; ++j) { sgate[j] = gt[j]; sgidx[j] = gi[j]; }
    }
    __syncthreads();

    // ---- weight build (k3 body), gate/gidx from LDS
    const int o = blockIdx.x;
    const int t = tix;
    float c[TOPKK][RR];
#pragma unroll
    for (int j = 0; j < TOPKK; ++j) {
        const float g = sgate[j];
        const int   p = sgidx[j];
#pragma unroll
        for (int r = 0; r < RR; ++r)
            c[j][r] = g * lup[(size_t)p * RR * DOUT + (size_t)r * DOUT + o];
    }
    const int d0 = t * 4;
    const float4 wv = *(const float4*)&W[(size_t)o * DIN + d0];
    float outv[4] = { wv.x, wv.y, wv.z, wv.w };
    float dwv[4]  = { 0.f, 0.f, 0.f, 0.f };
#pragma unroll
    for (int j = 0; j < TOPKK; ++j) {
        const int p = sgidx[j];
#pragma unroll
        for (int dd = 0; dd < 4; ++dd) {
            const float4 da = *(const float4*)&ldown[(size_t)p * DIN * RR + (size_t)(d0 + dd) * RR];
            const float4 db = *(const float4*)&ldown[(size_t)p * DIN * RR + (size_t)(d0 + dd) * RR + 4];
            dwv[dd] += da.x * c[j][0] + da.y * c[j][1] + da.z * c[j][2] + da.w * c[j][3]
                     + db.x * c[j][4] + db.y * c[j][5] + db.z * c[j][6] + db.w * c[j][7];
        }
    }
    bf16x4 b0 = { (__bf16)outv[0], (__bf16)outv[1], (__bf16)outv[2], (__bf16)outv[3] };
    bf16x4 b1 = { (__bf16)(outv[0] + dwv[0]), (__bf16)(outv[1] + dwv[1]),
                  (__bf16)(outv[2] + dwv[2]), (__bf16)(outv[3] + dwv[3]) };
    *(bf16x4*)&Wb0[(size_t)o * DIN + d0] = b0;
    *(bf16x4*)&Wb1[(size_t)o * DIN + d0] = b1;
}

// ---------------- K4: 128x256 GEMM, f32-A converted in-kernel -----------------
// Same as R11 except the lgkmcnt(0) drain moved AFTER computeSlab: the
// ds_write(s+1) drains while MFMAs run; invariant: A(s+1) writes complete
// before barrier#2(s) which precedes barrier#1(s+1) where slab s+1 is read.
__global__ __launch_bounds__(512, 4) void k4_gemm(const float* __restrict__ A,
                                                  const __bf16* __restrict__ B0,
                                                  const __bf16* __restrict__ B1,
                                                  float* __restrict__ C) {
    __shared__ ushort lds[36864];              // 72 KB; slab p at p*12288 ushorts
    const int bid = blockIdx.x;                // 0..511
    const int xcd = bid & 7;
    const int idx = bid >> 3;                  // 0..63
    const int tm  = xcd * 16 + (idx >> 2);     // 0..127 ; same-XCD blocks share A-panels
    const int tn  = idx & 3;                   // 0..3
    const __bf16* __restrict__ Bt = (tm >= 64) ? B1 : B0;   // rows >= 8192 get +delta

    const int tix  = threadIdx.x;
    const int lane = tix & 63;
    const int wid  = tix >> 6;                 // 0..7
    const int wm = wid >> 2, wn = wid & 3;     // 2M x 4N wave grid

    // ---- A staging (reg->cvt->ds_write)
    const int ar = tix >> 2;                   // 0..127
    const int ac = tix & 3;                    // 8-float chunk
    const f32x4* __restrict__ pA = (const f32x4*)(A + ((size_t)(tm * 128 + ar)) * 1024 + ac * 8);
    const int awrp  = tix >> 3;                        // rowpair 0..63
    const int awslot= ((tix & 3) + 4 * ((tix >> 2) & 1)) ^ (awrp & 7);
    const int awoff = awrp * 64 + awslot * 8;          // ushorts within A region

    // ---- B staging lane geometry (gload_lds, pre-swizzled global source):
    const int rpl  = lane >> 3;                // local rowpair 0..7
    const int sl   = (lane & 7) ^ rpl;         // logical c + 4*parity
    const int srow = rpl * 2 + (sl >> 2);      // 0..15
    const int sc   = sl & 3;                   // 16B k-chunk
    const char* gB = (const char*)Bt + ((size_t)(tn*256 + wid*32 + srow)) * 2048 + sc * 16;
    const int ldsBst = 4096 + wid * 1024;      // ushort idx within slab (B region)

    // ---- reader lane geometry (validated R5-R11):
    const int rhalf = (lane & 15) >> 1;
    const int slot  = ((lane >> 4) + 4 * (lane & 1)) ^ rhalf;
    const int aoff  = (wm * 32 + rhalf) * 64 + slot * 8;          // + p*12288 + mi*512
    const int boff  = 4096 + (wn * 32 + rhalf) * 64 + slot * 8;   // + p*12288 + ni*512

    f32x4 acc[4][4];
#pragma unroll
    for (int i = 0; i < 4; ++i)
#pragma unroll
        for (int j = 0; j < 4; ++j) acc[i][j] = (f32x4){0.f, 0.f, 0.f, 0.f};

    auto issueB = [&](int s) {
        const int p = s % 3;
        const size_t kb = (size_t)s * 64;      // 32 bf16 = 64 B per k-slab
#pragma unroll
        for (int j = 0; j < 2; ++j) {
            __builtin_amdgcn_global_load_lds(
                (const __attribute__((address_space(1))) void*)(gB + (size_t)j * 32768 + kb),
                (__attribute__((address_space(3))) void*)&lds[p * 12288 + ldsBst + j * 512],
                16, 0, 0);
        }
    };

    auto writeA = [&](int s, f32x4 a0, f32x4 a1) {
        const int p = s % 3;
        bf16x8 v = { (__bf16)a0[0], (__bf16)a0[1], (__bf16)a0[2], (__bf16)a0[3],
                     (__bf16)a1[0], (__bf16)a1[1], (__bf16)a1[2], (__bf16)a1[3] };
        *(bf16x8*)&lds[p * 12288 + awoff] = v;
    };

    auto computeSlab = [&](int s) {
        const int p = s % 3;
        const ushort* aB = &lds[p * 12288 + aoff];
        const ushort* bB = &lds[p * 12288 + boff];
        bf16x8 a[4], b[4];
#pragma unroll
        for (int mi = 0; mi < 4; ++mi) a[mi] = *(const bf16x8*)(aB + mi * 512);
#pragma unroll
        for (int ni = 0; ni < 4; ++ni) b[ni] = *(const bf16x8*)(bB + ni * 512);
        __builtin_amdgcn_s_setprio(1);
#pragma unroll
        for (int mi = 0; mi < 4; ++mi)
#pragma unroll
            for (int ni = 0; ni < 4; ++ni)
                acc[mi][ni] = __builtin_amdgcn_mfma_f32_16x16x32_bf16(
                    a[mi], b[ni], acc[mi][ni], 0, 0, 0);
        __builtin_amdgcn_s_setprio(0);
    };

    // ---- prologue: A(0),B(0),A(1),B(1) in flight; land+write A(0).
    f32x4 pa0 = pA[0], pa1 = pA[1];            // A(0)
    issueB(0);
    f32x4 na0 = pA[8], na1 = pA[9];            // A(1)
    issueB(1);
    asm volatile("s_waitcnt vmcnt(6)" ::: "memory");   // retire A(0) regs
    writeA(0, pa0, pa1);
    asm volatile("s_waitcnt lgkmcnt(0)" ::: "memory"); // A(0) visible pre-loop

#pragma unroll 1
    for (int s = 0; s < 32; ++s) {
        if (s < 31) {
            asm volatile("s_waitcnt vmcnt(2)" ::: "memory");  // retire B(s)+Areg(s+1)
            writeA(s + 1, na0, na1);
        } else {
            asm volatile("s_waitcnt vmcnt(0)" ::: "memory");
        }
        if (s < 30) {
            na0 = pA[(size_t)(s + 2) * 8];
            na1 = pA[(size_t)(s + 2) * 8 + 1];
            issueB(s + 2);
        }
        __builtin_amdgcn_s_barrier();                         // slab s fully staged
        asm volatile("" ::: "memory");
        computeSlab(s);
        asm volatile("" ::: "memory");
        asm volatile("s_waitcnt lgkmcnt(0)" ::: "memory");    // drain writeA(s+1), overlapped w/ MFMA
        __builtin_amdgcn_s_barrier();
    }

    // epilogue: D col = lane&15, row = (lane>>4)*4 + r
#pragma unroll
    for (int mi = 0; mi < 4; ++mi) {
#pragma unroll
        for (int r = 0; r < 4; ++r) {
            const int grow = tm * 128 + wm * 64 + mi * 16 + (lane >> 4) * 4 + r;
            float* cp = C + (size_t)grow * 1024 + tn * 256 + wn * 64 + (lane & 15);
#pragma unroll
            for (int ni = 0; ni < 4; ++ni) cp[ni * 16] = acc[mi][ni][r];
        }
    }
}

extern "C" void kernel_launch(void* const* d_in, const int* in_sizes, int n_in,
                              void* d_out, int out_size, void* d_ws, size_t ws_size,
                              hipStream_t stream) {
    const float* in     = (const float*)d_in[0];
    const float* W      = (const float*)d_in[1];
    const float* ldown  = (const float*)d_in[2];
    const float* lup    = (const float*)d_in[3];
    const float* lroute = (const float*)d_in[4];
    const int*   taskid = (const int*)d_in[5];
    float* out = (float*)d_out;

    // workspace carve (~12.1 MB)
    __bf16* Wb0     = (__bf16*)d_ws;                            // 2 MB
    __bf16* Wb1     = Wb0 + (size_t)DOUT * DIN;                 // 2 MB
    float*  partial2= (float*)(Wb1 + (size_t)DOUT * DIN);       // 32 KB
    float*  partial = partial2 + 8 * DIN + 64;                  // 8 MB

    kA_colsum<<<2048, 256, 0, stream>>>(in, partial);
    k1b_reduce<<<32, 256, 0, stream>>>(partial, partial2);
    k23_weights<<<1024, 256, 0, stream>>>(partial2, lroute, taskid, W, ldown, lup, Wb0, Wb1);
    k4_gemm<<<512, 512, 0, stream>>>(in, Wb0, Wb1, out);
}